// Round 8
// baseline (170.529 us; speedup 1.0000x reference)
//
#include <hip/hip_runtime.h>
#include <hip/hip_bf16.h>

// SelfAttentionLayer: B=64, N=1024, C=128, D=64
// R12: de-serialize the fused kernel (R11 measured: 80us, MfmaUtil 18.5%,
// VALU 31%, Occ 18.6% == grid-capped 2 blocks/CU, 3 barriers/kt lockstep).
//  (1) 64 q-rows/block (4 waves x 16 rows, R8-verified attn body),
//      grid 1024 -> 4 blocks/CU available.
//  (2) LDS 50KB (Xs 16K + KVb 16K + Qs[64][72] 9K + Pl[4][16][72] 9K)
//      -> 3 blocks/CU resident (lb(256,3)) for anti-phase overlap.
//  (3) T14 async stage split: issue x(kt+1) loads at top of proj(kt),
//      convert+write Xs after the barrier -> load latency hidden under
//      MFMA; 2 barriers/kt instead of 3.
//  (4) wprep kernel deleted: waves build their own W-frags from global
//      f32 (L2-hot 128KB); wql scoped to Q-phase; single kernel launch.
// All K/V frag scatter/read math verbatim from R11 (passed, absmax
// 0.03125); attn body verbatim from R8 (passed).

#define Bsz 64
#define Nsz 1024
#define Csz 128
#define Dsz 64

typedef __attribute__((ext_vector_type(8))) short short8;
typedef __attribute__((ext_vector_type(4))) float f32x4;

__device__ __forceinline__ unsigned short f2bf(float f) {
    union { float f; unsigned u; } v; v.f = f;
    unsigned r = v.u + 0x7FFF + ((v.u >> 16) & 1);
    return (unsigned short)(r >> 16);
}
__device__ __forceinline__ float bf2f(unsigned short h) {
    union { unsigned u; float f; } v; v.u = ((unsigned)h) << 16;
    return v.f;
}
__device__ __forceinline__ unsigned pack_bf16rn(float lo, float hi) {
    unsigned ulo = __float_as_uint(lo) + 0x8000u;
    unsigned uhi = __float_as_uint(hi) + 0x8000u;
    return __builtin_amdgcn_perm(uhi, ulo, 0x07060302u);
}

#define SCq (0.125f * 1.44269504f)     // 1/sqrt(D) * log2(e) folded into q
#define INV_SC (1.0f / (0.125f * 1.44269504f))

// ---------------- Fused kernel: QKV projection + flash attention ----------------
// grid 1024: b = blk&63 (XCD affinity: blk%8==b%8), qh = blk>>6 (0..15).
// Block = 64 q rows (qh*64..+63); 4 waves x 16 rows.
__global__ __launch_bounds__(256, 3) void fused_kernel(
    const float* __restrict__ x,
    const float* __restrict__ Wq, const float* __restrict__ bq,
    const float* __restrict__ Wk, const float* __restrict__ bk,
    const float* __restrict__ Wv, const float* __restrict__ bv,
    float* __restrict__ out)
{
    __shared__ short Xs[8192];         // x hi A-frags, 64 rows x 128 c (16 KB)
    __shared__ short KVb[2][4096];     // [0]=K frags / Q-phase x-lo; [1]=V frags
    __shared__ short Qs[64][72];       // q*SC bf16, row-padded (9 KB)
    __shared__ short Pl[4][16][72];    // per-wave P round-trip (9 KB)

    const int t    = threadIdx.x;
    const int lane = t & 63;
    const int l16  = lane & 15;
    const int quad = lane >> 4;
    const int wave = t >> 6;           // == dt for projection
    const int dt   = wave;
    const int b    = blockIdx.x & 63;
    const int qh   = blockIdx.x >> 6;
    const int d    = dt * 16 + l16;

    // ---- W B-frags from global f32 (replaces wprep kernel) ----
    // frag: lane(l16,quad), ksi block: rows c0=ksi*32+quad*8 .. +7, col d.
    short8 wqh[4], wkf[4], wvf[4];
    #pragma unroll
    for (int ksi = 0; ksi < 4; ksi++) {
        int c0 = ksi * 32 + quad * 8;
        #pragma unroll
        for (int j = 0; j < 8; j++) {
            wqh[ksi][j] = (short)f2bf(Wq[(c0 + j) * Dsz + d]);
            wkf[ksi][j] = (short)f2bf(Wk[(c0 + j) * Dsz + d]);
            wvf[ksi][j] = (short)f2bf(Wv[(c0 + j) * Dsz + d]);
        }
    }
    const float bqd = bq[d], bkd = bk[d], bvd = bv[d];

    // ================= Phase Q: project 64 q rows into Qs =================
    {
        // wql scoped here so its 16 VGPR die before the kt loop
        short8 wql[4];
        #pragma unroll
        for (int ksi = 0; ksi < 4; ksi++) {
            int c0 = ksi * 32 + quad * 8;
            #pragma unroll
            for (int j = 0; j < 8; j++) {
                float w = Wq[(c0 + j) * Dsz + d];
                unsigned short h = f2bf(w);
                wql[ksi][j] = (short)f2bf(w - bf2f(h));
            }
        }
        const long rowbase = (long)b * Nsz + qh * 64;
        {   // stage x hi -> Xs, lo -> KVb[0] (A-frag layout, verbatim R11)
            const int row = t & 63;
            const float* xrow = x + (rowbase + row) * Csz;
            short* xl = &KVb[0][0];
            #pragma unroll
            for (int p = 0; p < 4; p++) {
                int cb = (t >> 6) + p * 4;
                float4 a  = *(const float4*)(xrow + cb * 8);
                float4 b2 = *(const float4*)(xrow + cb * 8 + 4);
                float f[8] = {a.x, a.y, a.z, a.w, b2.x, b2.y, b2.z, b2.w};
                short8 hi, lo;
                #pragma unroll
                for (int i = 0; i < 8; i++) {
                    unsigned short h = f2bf(f[i]);
                    hi[i] = (short)h;
                    lo[i] = (short)f2bf(f[i] - bf2f(h));
                }
                int unit = ((row >> 4) * 4 + (cb >> 2)) * 64 + ((row & 15) | ((cb & 3) << 4));
                *(short8*)&Xs[unit * 8] = hi;
                *(short8*)&xl[unit * 8] = lo;
            }
        }
        __syncthreads();
        f32x4 aqc[4];
        #pragma unroll
        for (int i = 0; i < 4; i++) aqc[i] = (f32x4){0.f, 0.f, 0.f, 0.f};
        #pragma unroll
        for (int ksi = 0; ksi < 4; ksi++) {
            #pragma unroll
            for (int rt = 0; rt < 4; rt++) {
                short8 ah = *(const short8*)&Xs[((rt * 4 + ksi) * 64 + lane) * 8];
                short8 al = *(const short8*)&KVb[0][((rt * 4 + ksi) * 64 + lane) * 8];
                aqc[rt] = __builtin_amdgcn_mfma_f32_16x16x32_bf16(ah, wqh[ksi], aqc[rt], 0, 0, 0);
                aqc[rt] = __builtin_amdgcn_mfma_f32_16x16x32_bf16(al, wqh[ksi], aqc[rt], 0, 0, 0);
                aqc[rt] = __builtin_amdgcn_mfma_f32_16x16x32_bf16(ah, wql[ksi], aqc[rt], 0, 0, 0);
            }
        }
        #pragma unroll
        for (int rt = 0; rt < 4; rt++)
            #pragma unroll
            for (int r = 0; r < 4; r++) {
                float q = fmaxf(aqc[rt][r] + bqd, 0.f);
                Qs[rt * 16 + quad * 4 + r][d] = f2bf(q * SCq);
            }
        __syncthreads();
    }

    // Q A-frags (wave's own 16 rows) from Qs
    short8 aq[2];
    aq[0] = *(const short8*)&Qs[wave * 16 + l16][quad * 8];
    aq[1] = *(const short8*)&Qs[wave * 16 + l16][32 + quad * 8];

    f32x4 O[4];
    float lsum[4];
    #pragma unroll
    for (int i = 0; i < 4; i++) { O[i] = (f32x4){0.f,0.f,0.f,0.f}; lsum[i] = 0.f; }

    // K/V scatter constants (verbatim R11/R4 frag math)
    const int half  = dt >> 1;
    const int quadk = ((dt & 1) << 1) | (l16 >> 3);
    const int jk    = l16 & 7;
    const int ckk   = quad >> 1;
    const int quadp = (quad & 1) * 2;

    // x staging registers + helpers (T14 async split)
    float4 xa[4], xb[4];
    auto load_x = [&](int kt2) {
        const float* xrow = x + ((long)b * Nsz + kt2 * 64 + (t & 63)) * Csz;
        #pragma unroll
        for (int p = 0; p < 4; p++) {
            int cb = (t >> 6) + p * 4;
            xa[p] = *(const float4*)(xrow + cb * 8);
            xb[p] = *(const float4*)(xrow + cb * 8 + 4);
        }
    };
    auto write_xs = [&]() {
        const int row = t & 63;
        #pragma unroll
        for (int p = 0; p < 4; p++) {
            int cb = (t >> 6) + p * 4;
            float f[8] = {xa[p].x, xa[p].y, xa[p].z, xa[p].w,
                          xb[p].x, xb[p].y, xb[p].z, xb[p].w};
            short8 hi;
            #pragma unroll
            for (int i = 0; i < 8; i++) hi[i] = (short)f2bf(f[i]);
            int unit = ((row >> 4) * 4 + (cb >> 2)) * 64 + ((row & 15) | ((cb & 3) << 4));
            *(short8*)&Xs[unit * 8] = hi;
        }
    };

    // prologue: stage x(kt=0)
    load_x(0);
    write_xs();
    __syncthreads();

    // ================= kt loop: 2-barrier pipelined =================
    #pragma unroll 1
    for (int kt = 0; kt < 16; kt++) {
        // issue x loads for kt+1 now; land under proj+attn (~1500 cyc)
        if (kt < 15) load_x(kt + 1);

        // ---- proj: K/V tile from Xs (verbatim R11) ----
        f32x4 ak[4], av[4];
        #pragma unroll
        for (int i = 0; i < 4; i++) {
            ak[i] = (f32x4){0.f, 0.f, 0.f, 0.f};
            av[i] = (f32x4){0.f, 0.f, 0.f, 0.f};
        }
        #pragma unroll
        for (int ksi = 0; ksi < 4; ksi++) {
            #pragma unroll
            for (int rt = 0; rt < 4; rt++) {
                short8 ah = *(const short8*)&Xs[((rt * 4 + ksi) * 64 + lane) * 8];
                ak[rt] = __builtin_amdgcn_mfma_f32_16x16x32_bf16(ah, wkf[ksi], ak[rt], 0, 0, 0);
                av[rt] = __builtin_amdgcn_mfma_f32_16x16x32_bf16(ah, wvf[ksi], av[rt], 0, 0, 0);
            }
        }
        // scatter K to LDS frag layout (verbatim R11)
        float vv[4][4];   // [r][rt]
        #pragma unroll
        for (int rt = 0; rt < 4; rt++) {
            #pragma unroll
            for (int r = 0; r < 4; r++) {
                float kv = fmaxf(ak[rt][r] + bkd, 0.f);
                vv[r][rt] = fmaxf(av[rt][r] + bvd, 0.f);
                KVb[0][(rt * 2 + half) * 512 + (quadk * 16 + quad * 4 + r) * 8 + jk] = f2bf(kv);
            }
        }
        // pack V to LDS frag layout (verbatim R11)
        uint4 o0 = make_uint4(pack_bf16rn(vv[0][0], vv[0][1]), pack_bf16rn(vv[0][2], vv[0][3]),
                              pack_bf16rn(vv[1][0], vv[1][1]), pack_bf16rn(vv[1][2], vv[1][3]));
        uint4 o1 = make_uint4(pack_bf16rn(vv[2][0], vv[2][1]), pack_bf16rn(vv[2][2], vv[2][3]),
                              pack_bf16rn(vv[3][0], vv[3][1]), pack_bf16rn(vv[3][2], vv[3][3]));
        *(uint4*)&KVb[1][(dt * 2 + ckk) * 512 + (quadp * 16 + l16) * 8]      = o0;
        *(uint4*)&KVb[1][(dt * 2 + ckk) * 512 + (quadp * 16 + 16 + l16) * 8] = o1;

        __syncthreads();   // B1: KVb ready; Xs reads complete

        // convert+write Xs(kt+1) — x loads landed under proj
        if (kt < 15) write_xs();

        // ---- attn body (verbatim R8, 16 rows/wave) ----
        short8 kf[4][2];
        #pragma unroll
        for (int kb = 0; kb < 4; kb++) {
            kf[kb][0] = *(const short8*)&KVb[0][(kb * 2 + 0) * 512 + lane * 8];
            kf[kb][1] = *(const short8*)&KVb[0][(kb * 2 + 1) * 512 + lane * 8];
        }
        f32x4 sc[4];
        #pragma unroll
        for (int kb = 0; kb < 4; kb++) {
            f32x4 z = (f32x4){0.f, 0.f, 0.f, 0.f};
            z = __builtin_amdgcn_mfma_f32_16x16x32_bf16(aq[0], kf[kb][0], z, 0, 0, 0);
            z = __builtin_amdgcn_mfma_f32_16x16x32_bf16(aq[1], kf[kb][1], z, 0, 0, 0);
            sc[kb] = z;
        }
        short8 bvf[2][4];
        #pragma unroll
        for (int cb = 0; cb < 4; cb++) {
            bvf[0][cb] = *(const short8*)&KVb[1][(cb * 2 + 0) * 512 + lane * 8];
            bvf[1][cb] = *(const short8*)&KVb[1][(cb * 2 + 1) * 512 + lane * 8];
        }
        #pragma unroll
        for (int r = 0; r < 4; r++) {
            float p0 = __builtin_amdgcn_exp2f(sc[0][r]);
            float p1 = __builtin_amdgcn_exp2f(sc[1][r]);
            float p2 = __builtin_amdgcn_exp2f(sc[2][r]);
            float p3 = __builtin_amdgcn_exp2f(sc[3][r]);
            lsum[r] += (p0 + p1) + (p2 + p3);
            *(uint2*)&Pl[wave][quad * 4 + r][l16 * 4] =
                make_uint2(pack_bf16rn(p0, p1), pack_bf16rn(p2, p3));
        }
        #pragma unroll
        for (int ck = 0; ck < 2; ck++) {
            short8 ap = *(const short8*)&Pl[wave][l16][ck * 32 + quad * 8];
            #pragma unroll
            for (int cb = 0; cb < 4; cb++) {
                O[cb] = __builtin_amdgcn_mfma_f32_16x16x32_bf16(ap, bvf[ck][cb], O[cb], 0, 0, 0);
            }
        }

        __syncthreads();   // B2: KVb reads + Xs(kt+1) writes complete
    }

    // deferred row-sum reduction (lanes sharing a row: same quad, l16 0..15)
    #pragma unroll
    for (int r = 0; r < 4; r++)
        #pragma unroll
        for (int off = 1; off < 16; off <<= 1)
            lsum[r] += __shfl_xor(lsum[r], off);

    // epilogue: out = O/l + q (q residual from Qs LDS, same bits)
    #pragma unroll
    for (int r = 0; r < 4; r++) {
        float rl = 1.0f / lsum[r];
        int lrow = wave * 16 + quad * 4 + r;
        long nrow = (long)b * Nsz + qh * 64 + lrow;
        #pragma unroll
        for (int cb = 0; cb < 4; cb++) {
            int d2 = cb * 16 + l16;
            float qv = bf2f((unsigned short)Qs[lrow][d2]) * INV_SC;
            out[nrow * Dsz + d2] = O[cb][r] * rl + qv;
        }
    }
}

extern "C" void kernel_launch(void* const* d_in, const int* in_sizes, int n_in,
                              void* d_out, int out_size, void* d_ws, size_t ws_size,
                              hipStream_t stream) {
    const float* x  = (const float*)d_in[0];
    const float* Wq = (const float*)d_in[1];
    const float* bq = (const float*)d_in[2];
    const float* Wk = (const float*)d_in[3];
    const float* bk = (const float*)d_in[4];
    const float* Wv = (const float*)d_in[5];
    const float* bv = (const float*)d_in[6];
    float* out = (float*)d_out;

    fused_kernel<<<dim3(1024), dim3(256), 0, stream>>>(
        x, Wq, bq, Wk, bk, Wv, bv, out);
}

// Round 9
// 139.320 us; speedup vs baseline: 1.2240x; 1.2240x over previous
//
#include <hip/hip_runtime.h>
#include <hip/hip_bf16.h>

// SelfAttentionLayer: B=64, N=1024, C=128, D=64
// R13: R12 post-mortem: fused 80->117us was EXACTLY the 8x->16x K/V-proj
// redundancy increase (37->54 GF at fixed ~19% MfmaUtil). Occupancy was
// never the lever; barrier-window size is.
// This round: back to R11 tile (128 q rows/block, grid 512, 8x redundancy)
// with ONE barrier per kt via full double-buffering:
//   per kt: load_x(kt+2) issue -> proj(kt+1)->KVb[nxt] -> attn(kt) from
//   KVb[cur] -> write_xs(kt+2)->Xs[cur] -> __syncthreads.
// proj MFMA + attn MFMA + exp VALU + LDS + global loads co-scheduled in a
// single ~64-MFMA window; x-load latency hidden under the whole body (T14).
// LDS 73KB -> 2 blocks/CU: Xs[2] 32K + KVb[2] 32K + Pl[4][16][72] 9K,
// Qs[128][64] aliased into Xs[1] during Phase Q (q-residual -> 16 VGPR).
// kt-loop x staging uses pack_bf16rn uint4 stores (3x fewer VALU ops;
// +-1ulp bf16 tie diff vs f2bf, inside threshold). K/V frag scatter/read
// math verbatim from R11 (passed, absmax 0.03125).

#define Bsz 64
#define Nsz 1024
#define Csz 128
#define Dsz 64

typedef __attribute__((ext_vector_type(8))) short short8;
typedef __attribute__((ext_vector_type(4))) float f32x4;

__device__ __forceinline__ unsigned short f2bf(float f) {
    union { float f; unsigned u; } v; v.f = f;
    unsigned r = v.u + 0x7FFF + ((v.u >> 16) & 1);
    return (unsigned short)(r >> 16);
}
__device__ __forceinline__ float bf2f(unsigned short h) {
    union { unsigned u; float f; } v; v.u = ((unsigned)h) << 16;
    return v.f;
}
__device__ __forceinline__ unsigned pack_bf16rn(float lo, float hi) {
    unsigned ulo = __float_as_uint(lo) + 0x8000u;
    unsigned uhi = __float_as_uint(hi) + 0x8000u;
    return __builtin_amdgcn_perm(uhi, ulo, 0x07060302u);
}

#define SCq (0.125f * 1.44269504f)     // 1/sqrt(D) * log2(e) folded into q
#define INV_SC (1.0f / (0.125f * 1.44269504f))

// ---------------- Fused kernel: QKV projection + flash attention ----------------
// grid 512: b = blk&63 (XCD affinity: blk%8==b%8), qh = blk>>6 (0..7).
// Block = 128 q rows; 4 waves x 32 rows (2 s-strips of 16).
__global__ __launch_bounds__(256, 2) void fused_kernel(
    const float* __restrict__ x,
    const float* __restrict__ Wq, const float* __restrict__ bq,
    const float* __restrict__ Wk, const float* __restrict__ bk,
    const float* __restrict__ Wv, const float* __restrict__ bv,
    float* __restrict__ out)
{
    __shared__ short Xs[2][8192];      // x bf16 A-frag tiles, double-buffered (32 KB)
    __shared__ short KVb[2][8192];     // per buf: [0,4096)=K frags, [4096,8192)=V (32 KB)
    __shared__ short Pl[4][16][72];    // per-wave P round-trip, per-s reuse (9 KB)

    const int t    = threadIdx.x;
    const int lane = t & 63;
    const int l16  = lane & 15;
    const int quad = lane >> 4;
    const int wave = t >> 6;           // == dt for projection
    const int dt   = wave;
    const int b    = blockIdx.x & 63;
    const int qh   = blockIdx.x >> 6;
    const int d    = dt * 16 + l16;

    // ---- W B-frags from global f32 (no wprep kernel) ----
    short8 wqh[4], wkf[4], wvf[4];
    #pragma unroll
    for (int ksi = 0; ksi < 4; ksi++) {
        int c0 = ksi * 32 + quad * 8;
        #pragma unroll
        for (int j = 0; j < 8; j++) {
            wqh[ksi][j] = (short)f2bf(Wq[(c0 + j) * Dsz + d]);
            wkf[ksi][j] = (short)f2bf(Wk[(c0 + j) * Dsz + d]);
            wvf[ksi][j] = (short)f2bf(Wv[(c0 + j) * Dsz + d]);
        }
    }
    const float bqd = bq[d], bkd = bk[d], bvd = bv[d];

    // Qs aliased into Xs[1] during Phase Q only (128 rows x 64, unpadded)
    short (*Qs)[64] = (short(*)[64])&Xs[1][0];

    // ================= Phase Q: project 128 q rows into Qs =================
    {
        short8 wql[4];   // scoped: dies before kt loop
        #pragma unroll
        for (int ksi = 0; ksi < 4; ksi++) {
            int c0 = ksi * 32 + quad * 8;
            #pragma unroll
            for (int j = 0; j < 8; j++) {
                float w = Wq[(c0 + j) * Dsz + d];
                unsigned short h = f2bf(w);
                wql[ksi][j] = (short)f2bf(w - bf2f(h));
            }
        }
        #pragma unroll 1
        for (int h64 = 0; h64 < 2; h64++) {
            const long rowbase = (long)b * Nsz + qh * 128 + h64 * 64;
            {   // stage x hi -> Xs[0], lo -> KVb[0] (A-frag layout, verbatim R11)
                const int row = t & 63;
                const float* xrow = x + (rowbase + row) * Csz;
                short* xl = &KVb[0][0];
                #pragma unroll
                for (int p = 0; p < 4; p++) {
                    int cb = (t >> 6) + p * 4;
                    float4 a  = *(const float4*)(xrow + cb * 8);
                    float4 b2 = *(const float4*)(xrow + cb * 8 + 4);
                    float f[8] = {a.x, a.y, a.z, a.w, b2.x, b2.y, b2.z, b2.w};
                    short8 hi, lo;
                    #pragma unroll
                    for (int i = 0; i < 8; i++) {
                        unsigned short h = f2bf(f[i]);
                        hi[i] = (short)h;
                        lo[i] = (short)f2bf(f[i] - bf2f(h));
                    }
                    int unit = ((row >> 4) * 4 + (cb >> 2)) * 64 + ((row & 15) | ((cb & 3) << 4));
                    *(short8*)&Xs[0][unit * 8] = hi;
                    *(short8*)&xl[unit * 8] = lo;
                }
            }
            __syncthreads();
            f32x4 aqc[4];
            #pragma unroll
            for (int i = 0; i < 4; i++) aqc[i] = (f32x4){0.f, 0.f, 0.f, 0.f};
            #pragma unroll
            for (int ksi = 0; ksi < 4; ksi++) {
                #pragma unroll
                for (int rt = 0; rt < 4; rt++) {
                    short8 ah = *(const short8*)&Xs[0][((rt * 4 + ksi) * 64 + lane) * 8];
                    short8 al = *(const short8*)&KVb[0][((rt * 4 + ksi) * 64 + lane) * 8];
                    aqc[rt] = __builtin_amdgcn_mfma_f32_16x16x32_bf16(ah, wqh[ksi], aqc[rt], 0, 0, 0);
                    aqc[rt] = __builtin_amdgcn_mfma_f32_16x16x32_bf16(al, wqh[ksi], aqc[rt], 0, 0, 0);
                    aqc[rt] = __builtin_amdgcn_mfma_f32_16x16x32_bf16(ah, wql[ksi], aqc[rt], 0, 0, 0);
                }
            }
            #pragma unroll
            for (int rt = 0; rt < 4; rt++)
                #pragma unroll
                for (int r = 0; r < 4; r++) {
                    float q = fmaxf(aqc[rt][r] + bqd, 0.f);
                    Qs[h64 * 64 + rt * 16 + quad * 4 + r][d] = f2bf(q * SCq);
                }
            __syncthreads();
        }
    }

    // Q A-frags (wave's 32 rows) + q-residual to registers (frees Qs/Xs[1])
    short8 aq[2][2];
    uint2  qres[2][4];
    #pragma unroll
    for (int s = 0; s < 2; s++) {
        aq[s][0] = *(const short8*)&Qs[wave * 32 + s * 16 + l16][quad * 8];
        aq[s][1] = *(const short8*)&Qs[wave * 32 + s * 16 + l16][32 + quad * 8];
        #pragma unroll
        for (int r = 0; r < 4; r++) {
            int row = wave * 32 + s * 16 + quad * 4 + r;
            unsigned c0 = (unsigned short)Qs[row][l16];
            unsigned c1 = (unsigned short)Qs[row][16 + l16];
            unsigned c2 = (unsigned short)Qs[row][32 + l16];
            unsigned c3 = (unsigned short)Qs[row][48 + l16];
            qres[s][r] = make_uint2(c0 | (c1 << 16), c2 | (c3 << 16));
        }
    }

    // ---- staging helpers (T14 async split) ----
    float4 xa[4], xb[4];
    auto load_x = [&](int kt2) {
        const float* xrow = x + ((long)b * Nsz + kt2 * 64 + (t & 63)) * Csz;
        #pragma unroll
        for (int p = 0; p < 4; p++) {
            int cb = (t >> 6) + p * 4;
            xa[p] = *(const float4*)(xrow + cb * 8);
            xb[p] = *(const float4*)(xrow + cb * 8 + 4);
        }
    };
    auto write_xs = [&](short* dst) {
        const int row = t & 63;
        #pragma unroll
        for (int p = 0; p < 4; p++) {
            int cb = (t >> 6) + p * 4;
            int unit = ((row >> 4) * 4 + (cb >> 2)) * 64 + ((row & 15) | ((cb & 3) << 4));
            *(uint4*)&dst[unit * 8] = make_uint4(
                pack_bf16rn(xa[p].x, xa[p].y), pack_bf16rn(xa[p].z, xa[p].w),
                pack_bf16rn(xb[p].x, xb[p].y), pack_bf16rn(xb[p].z, xb[p].w));
        }
    };

    // K/V scatter constants (verbatim R11 frag math)
    const int half  = dt >> 1;
    const int quadk = ((dt & 1) << 1) | (l16 >> 3);
    const int jk    = l16 & 7;
    const int ckk   = quad >> 1;
    const int quadp = (quad & 1) * 2;

    auto proj = [&](const short* Xsrc, short* KV) {
        f32x4 ak[4], av[4];
        #pragma unroll
        for (int i = 0; i < 4; i++) {
            ak[i] = (f32x4){0.f, 0.f, 0.f, 0.f};
            av[i] = (f32x4){0.f, 0.f, 0.f, 0.f};
        }
        #pragma unroll
        for (int ksi = 0; ksi < 4; ksi++) {
            #pragma unroll
            for (int rt = 0; rt < 4; rt++) {
                short8 ah = *(const short8*)&Xsrc[((rt * 4 + ksi) * 64 + lane) * 8];
                ak[rt] = __builtin_amdgcn_mfma_f32_16x16x32_bf16(ah, wkf[ksi], ak[rt], 0, 0, 0);
                av[rt] = __builtin_amdgcn_mfma_f32_16x16x32_bf16(ah, wvf[ksi], av[rt], 0, 0, 0);
            }
        }
        float vv[4][4];   // [r][rt]
        #pragma unroll
        for (int rt = 0; rt < 4; rt++) {
            #pragma unroll
            for (int r = 0; r < 4; r++) {
                float kv = fmaxf(ak[rt][r] + bkd, 0.f);
                vv[r][rt] = fmaxf(av[rt][r] + bvd, 0.f);
                KV[(rt * 2 + half) * 512 + (quadk * 16 + quad * 4 + r) * 8 + jk] = f2bf(kv);
            }
        }
        uint4 o0 = make_uint4(pack_bf16rn(vv[0][0], vv[0][1]), pack_bf16rn(vv[0][2], vv[0][3]),
                              pack_bf16rn(vv[1][0], vv[1][1]), pack_bf16rn(vv[1][2], vv[1][3]));
        uint4 o1 = make_uint4(pack_bf16rn(vv[2][0], vv[2][1]), pack_bf16rn(vv[2][2], vv[2][3]),
                              pack_bf16rn(vv[3][0], vv[3][1]), pack_bf16rn(vv[3][2], vv[3][3]));
        *(uint4*)&KV[4096 + (dt * 2 + ckk) * 512 + (quadp * 16 + l16) * 8]      = o0;
        *(uint4*)&KV[4096 + (dt * 2 + ckk) * 512 + (quadp * 16 + 16 + l16) * 8] = o1;
    };

    // ---- prologue: fill Xs[0]=x(0), Xs[1]=x(1), KVb[0]=proj(0) ----
    load_x(0);
    write_xs(&Xs[0][0]);               // Xs[0] free since Phase Q barrier
    load_x(1);
    __syncthreads();                   // all Qs reads done; Xs[0] staged
    proj(&Xs[0][0], &KVb[0][0]);
    write_xs(&Xs[1][0]);               // overwrites Qs (extracted to regs)
    __syncthreads();

    f32x4 O[2][4];
    float lsum[2][4];
    #pragma unroll
    for (int s = 0; s < 2; s++)
        #pragma unroll
        for (int i = 0; i < 4; i++) { O[s][i] = (f32x4){0.f,0.f,0.f,0.f}; lsum[s][i] = 0.f; }

    // ================= kt loop: ONE barrier per kt =================
    #pragma unroll 1
    for (int kt = 0; kt < 16; kt++) {
        const int cur = kt & 1;
        if (kt < 14) load_x(kt + 2);                       // issue early
        if (kt < 15) proj(&Xs[cur ^ 1][0], &KVb[cur ^ 1][0]);

        // ---- attn(kt) from KVb[cur] (R11 math, per-s Pl reuse) ----
        short8 kf[4][2];
        #pragma unroll
        for (int kb = 0; kb < 4; kb++) {
            kf[kb][0] = *(const short8*)&KVb[cur][(kb * 2 + 0) * 512 + lane * 8];
            kf[kb][1] = *(const short8*)&KVb[cur][(kb * 2 + 1) * 512 + lane * 8];
        }
        f32x4 sc[2][4];
        #pragma unroll
        for (int s = 0; s < 2; s++) {
            #pragma unroll
            for (int kb = 0; kb < 4; kb++) {
                f32x4 z = (f32x4){0.f, 0.f, 0.f, 0.f};
                z = __builtin_amdgcn_mfma_f32_16x16x32_bf16(aq[s][0], kf[kb][0], z, 0, 0, 0);
                z = __builtin_amdgcn_mfma_f32_16x16x32_bf16(aq[s][1], kf[kb][1], z, 0, 0, 0);
                sc[s][kb] = z;
            }
        }
        short8 bvf[2][4];
        #pragma unroll
        for (int cb = 0; cb < 4; cb++) {
            bvf[0][cb] = *(const short8*)&KVb[cur][4096 + (cb * 2 + 0) * 512 + lane * 8];
            bvf[1][cb] = *(const short8*)&KVb[cur][4096 + (cb * 2 + 1) * 512 + lane * 8];
        }
        #pragma unroll
        for (int s = 0; s < 2; s++) {
            #pragma unroll
            for (int r = 0; r < 4; r++) {
                float p0 = __builtin_amdgcn_exp2f(sc[s][0][r]);
                float p1 = __builtin_amdgcn_exp2f(sc[s][1][r]);
                float p2 = __builtin_amdgcn_exp2f(sc[s][2][r]);
                float p3 = __builtin_amdgcn_exp2f(sc[s][3][r]);
                lsum[s][r] += (p0 + p1) + (p2 + p3);
                *(uint2*)&Pl[wave][quad * 4 + r][l16 * 4] =
                    make_uint2(pack_bf16rn(p0, p1), pack_bf16rn(p2, p3));
            }
            #pragma unroll
            for (int ck = 0; ck < 2; ck++) {
                short8 ap = *(const short8*)&Pl[wave][l16][ck * 32 + quad * 8];
                #pragma unroll
                for (int cb = 0; cb < 4; cb++) {
                    O[s][cb] = __builtin_amdgcn_mfma_f32_16x16x32_bf16(ap, bvf[ck][cb], O[s][cb], 0, 0, 0);
                }
            }
        }

        if (kt < 14) write_xs(&Xs[cur][0]);                // x loads landed under body
        __syncthreads();                                   // the ONE barrier
    }

    // deferred row-sum reduction (lanes sharing a row: same quad, l16 0..15)
    #pragma unroll
    for (int s = 0; s < 2; s++)
        #pragma unroll
        for (int r = 0; r < 4; r++)
            #pragma unroll
            for (int off = 1; off < 16; off <<= 1)
                lsum[s][r] += __shfl_xor(lsum[s][r], off);

    // epilogue: out = O/l + q (q residual from qres registers, same bits)
    #pragma unroll
    for (int s = 0; s < 2; s++) {
        #pragma unroll
        for (int r = 0; r < 4; r++) {
            float rl = 1.0f / lsum[s][r];
            long nrow = (long)b * Nsz + qh * 128 + wave * 32 + s * 16 + quad * 4 + r;
            #pragma unroll
            for (int cb = 0; cb < 4; cb++) {
                unsigned u = (cb < 2) ? qres[s][r].x : qres[s][r].y;
                unsigned short hw = (cb & 1) ? (unsigned short)(u >> 16)
                                             : (unsigned short)(u & 0xffff);
                out[nrow * Dsz + cb * 16 + l16] = O[s][cb][r] * rl + bf2f(hw) * INV_SC;
            }
        }
    }
}

extern "C" void kernel_launch(void* const* d_in, const int* in_sizes, int n_in,
                              void* d_out, int out_size, void* d_ws, size_t ws_size,
                              hipStream_t stream) {
    const float* x  = (const float*)d_in[0];
    const float* Wq = (const float*)d_in[1];
    const float* bq = (const float*)d_in[2];
    const float* Wk = (const float*)d_in[3];
    const float* bk = (const float*)d_in[4];
    const float* Wv = (const float*)d_in[5];
    const float* bv = (const float*)d_in[6];
    float* out = (float*)d_out;

    fused_kernel<<<dim3(512), dim3(256), 0, stream>>>(
        x, Wq, bq, Wk, bk, Wv, bv, out);
}